// Round 13
// baseline (209.751 us; speedup 1.0000x reference)
//
#include <hip/hip_runtime.h>

#define TWO_PI_F 6.283185307179586f

__device__ __forceinline__ float clamp02pi(float x) {
    return fminf(fmaxf(x, 0.0f), TWO_PI_F);
}

__device__ __forceinline__ float2 cmul(const float2 a, const float2 b) {
    return make_float2(a.x * b.x - a.y * b.y, a.x * b.y + a.y * b.x);
}
__device__ __forceinline__ float2 cadd(const float2 a, const float2 b) {
    return make_float2(a.x + b.x, a.y + b.y);
}
__device__ __forceinline__ float2 cscale(const float s, const float2 a) {
    return make_float2(s * a.x, s * a.y);
}
__device__ __forceinline__ float2 imul(const float r, const float2 e) {  // i*r*e
    return make_float2(-r * e.y, r * e.x);
}

// ---------------------------------------------------------------------------
// Kernel 1: fused coef + step-composition (verbatim R12 — verified,
// absmax 3.7e-9). Row r of M_step = O1*O0*E1*E0 is a band of 4 complex
// coefs; layout for the pair-thread mesh (t = r>>1):
//   even r: Mc[i*1024 +       t] = h0,  Mc[i*1024 + 256 + t] = h1
//   odd  r: Mc[i*1024 + 512 + t] = h0,  Mc[i*1024 + 768 + t] = h1
// ---------------------------------------------------------------------------
__global__ __launch_bounds__(512) void compose_kernel(
    const float* __restrict__ pe, const float* __restrict__ po,
    const float* __restrict__ le, const float* __restrict__ ie,
    const float* __restrict__ lo, const float* __restrict__ io,
    float4* __restrict__ Mc)
{
    const int i = blockIdx.x;    // step 0..255
    const int t = threadIdx.x;   // 0..511

    __shared__ float4 sE[2][256];   // [sub-layer][even pair]
    __shared__ float4 sO[2][256];   // [sub-layer][odd pair]; 255 = identity

    {
        const int sub = t >> 8, pp = t & 255;
        const int k = 2 * i + sub;
        const int idx = k * 256 + pp;
        float s, c;
        __sincosf(clamp02pi(pe[idx]), &s, &c);
        const float a = sqrtf(1.0f - le[idx]);
        sE[sub][pp] = make_float4(c, s, a * sqrtf(0.5f + ie[idx]),
                                        a * sqrtf(0.5f - ie[idx]));
        float4 q = make_float4(1.0f, 0.0f, 1.0f, 0.0f);
        if (pp < 255) {
            const int odx = k * 255 + pp;
            float so, co;
            __sincosf(clamp02pi(po[odx]), &so, &co);
            const float ao = sqrtf(1.0f - lo[odx]);
            q = make_float4(co, so, ao * sqrtf(0.5f + io[odx]),
                                    ao * sqrtf(0.5f - io[odx]));
        }
        sO[sub][pp] = q;
    }
    __syncthreads();

    const int r = t;
    float2 f0, f1, f2, f3;
    if (r == 0) {
        const float4 q1 = sE[1][0], q0 = sE[0][0];
        const float2 e1 = make_float2(q1.x, q1.y);
        const float2 e0 = make_float2(q0.x, q0.y);
        const float2 v2 = cscale(q1.z, e1);
        const float2 v3 = make_float2(0.0f, q1.w);
        f2 = cadd(cmul(v2, cscale(q0.z, e0)), cmul(v3, imul(q0.w, e0)));
        f3 = cadd(cmul(v2, make_float2(0.0f, q0.w)), cscale(q0.z, v3));
        f0 = make_float2(0.0f, 0.0f);
        f1 = make_float2(0.0f, 0.0f);
    } else {
        const int pidx = (r - 1) >> 1;
        const int qidx = min(pidx + 1, 255);      // r=511: u2==0, value unused
        const float4 qO1 = sO[1][pidx], qO0 = sO[0][pidx];
        const float2 eO1 = make_float2(qO1.x, qO1.y);
        const float2 eO0 = make_float2(qO0.x, qO0.y);
        float2 w1, w2;
        if (r & 1) { w1 = cscale(qO1.z, eO1); w2 = make_float2(0.0f, qO1.w); }
        else       { w1 = imul(qO1.w, eO1);   w2 = make_float2(qO1.z, 0.0f); }
        const float2 u1 = cadd(cmul(w1, cscale(qO0.z, eO0)),
                               cmul(w2, imul(qO0.w, eO0)));
        const float2 u2 = cadd(cmul(w1, make_float2(0.0f, qO0.w)),
                               cscale(qO0.z, w2));
        const float4 qE1p = sE[1][pidx], qE1q = sE[1][qidx];
        const float4 qE0p = sE[0][pidx], qE0q = sE[0][qidx];
        const float2 eE1p = make_float2(qE1p.x, qE1p.y);
        const float2 eE1q = make_float2(qE1q.x, qE1q.y);
        const float2 eE0p = make_float2(qE0p.x, qE0p.y);
        const float2 eE0q = make_float2(qE0q.x, qE0q.y);
        const float2 v0 = cmul(u1, imul(qE1p.w, eE1p));
        const float2 v1 = cscale(qE1p.z, u1);
        const float2 v2 = cmul(u2, cscale(qE1q.z, eE1q));
        const float2 v3 = cmul(u2, make_float2(0.0f, qE1q.w));
        f0 = cadd(cmul(v0, cscale(qE0p.z, eE0p)), cmul(v1, imul(qE0p.w, eE0p)));
        f1 = cadd(cmul(v0, make_float2(0.0f, qE0p.w)), cscale(qE0p.z, v1));
        f2 = cadd(cmul(v2, cscale(qE0q.z, eE0q)), cmul(v3, imul(qE0q.w, eE0q)));
        f3 = cadd(cmul(v2, make_float2(0.0f, qE0q.w)), cscale(qE0q.z, v3));
    }
    const int tp = r >> 1;
    const int base = i * 1024 + ((r & 1) ? 512 : 0) + tp;
    Mc[base]       = make_float4(f0.x, f0.y, f1.x, f1.y);
    Mc[base + 256] = make_float4(f2.x, f2.y, f3.x, f3.y);
}

// Banded row apply: out = c0.xy*a + c0.zw*b + c1.xy*d + c1.zw*e (complex).
__device__ __forceinline__ float2 row4(const float4 c0, const float4 c1,
                                       const float2 a, const float2 b,
                                       const float2 d, const float2 e)
{
    float re = c0.x * a.x - c0.y * a.y;
    float im = c0.x * a.y + c0.y * a.x;
    re += c0.z * b.x - c0.w * b.y;  im += c0.z * b.y + c0.w * b.x;
    re += c1.x * d.x - c1.y * d.y;  im += c1.x * d.y + c1.y * d.x;
    re += c1.z * e.x - c1.w * e.y;  im += c1.z * e.y + c1.w * e.x;
    return make_float2(re, im);
}

// ---------------------------------------------------------------------------
// Kernel 2: pair-thread banded scan, TWO columns per thread.
// Grid 256 blocks x 256 threads = full 256-CU coverage (1 block/CU, 4 waves).
// Block b owns columns (2b, 2b+1); thread t owns rows (2t, 2t+1) of BOTH in
// registers. The band coefs are column-independent, so each 64 B coef read
// is reused for 2 columns — halves the L2 coef stream vs R12 (the measured
// bottleneck: 585 -> 290 cyc/step/CU) and doubles per-thread FMA (64/step).
// State in double-buffered LDS (S[buf][col][pair]); ONE barrier per step.
//   row 2t   (even): row4(c0, c1, below.T, below.B, T, B)
//   row 2t+1 (odd) : row4(c2, c3, T, B, above.T, above.B)
// Edge clamps feed finite garbage into exactly-zero band coefs (rows 0/511)
// — verified R10-R12. Coefs in named registers (R8-R10 spill lesson).
// ---------------------------------------------------------------------------
__global__ __launch_bounds__(256) void mesh_pair2_kernel(
    const float4* __restrict__ Mc,
    const float* __restrict__ pout,
    float* __restrict__ out, const int out_size)
{
    const int t = threadIdx.x;   // row-pair 0..255
    const int b = blockIdx.x;    // column-pair 0..255
    const int cA = 2 * b, cB = 2 * b + 1;

    __shared__ float4 S[2][2][256];   // [buf][col][pair] = {T.x,T.y,B.x,B.y}

    float2 T0 = make_float2((2 * t     == cA) ? 1.0f : 0.0f, 0.0f);
    float2 B0 = make_float2((2 * t + 1 == cA) ? 1.0f : 0.0f, 0.0f);
    float2 T1 = make_float2((2 * t     == cB) ? 1.0f : 0.0f, 0.0f);
    float2 B1 = make_float2((2 * t + 1 == cB) ? 1.0f : 0.0f, 0.0f);
    S[0][0][t] = make_float4(T0.x, T0.y, B0.x, B0.y);
    S[0][1][t] = make_float4(T1.x, T1.y, B1.x, B1.y);

    const int tm = (t > 0) ? t - 1 : 0;
    const int tp = (t < 255) ? t + 1 : 255;

    // current-step coefs (named registers, not arrays — spill-proof)
    float4 c0 = Mc[t], c1 = Mc[256 + t], c2 = Mc[512 + t], c3 = Mc[768 + t];
    __syncthreads();

#pragma unroll 1
    for (int i = 0; i < 256; ++i) {
        // prefetch next step's coefs (wraps at 255; harmless)
        const int nb = ((i + 1) & 255) * 1024 + t;
        const float4 n0 = Mc[nb],       n1 = Mc[nb + 256],
                     n2 = Mc[nb + 512], n3 = Mc[nb + 768];

        const int cur = i & 1, nxt = (i + 1) & 1;
        const float4 bel0 = S[cur][0][tm], abv0 = S[cur][0][tp];
        const float4 bel1 = S[cur][1][tm], abv1 = S[cur][1][tp];

        const float2 Ye0 = row4(c0, c1, make_float2(bel0.x, bel0.y),
                                        make_float2(bel0.z, bel0.w), T0, B0);
        const float2 Yo0 = row4(c2, c3, T0, B0, make_float2(abv0.x, abv0.y),
                                                make_float2(abv0.z, abv0.w));
        const float2 Ye1 = row4(c0, c1, make_float2(bel1.x, bel1.y),
                                        make_float2(bel1.z, bel1.w), T1, B1);
        const float2 Yo1 = row4(c2, c3, T1, B1, make_float2(abv1.x, abv1.y),
                                                make_float2(abv1.z, abv1.w));
        T0 = Ye0; B0 = Yo0; T1 = Ye1; B1 = Yo1;
        S[nxt][0][t] = make_float4(T0.x, T0.y, B0.x, B0.y);
        S[nxt][1][t] = make_float4(T1.x, T1.y, B1.x, B1.y);
        __syncthreads();

        c0 = n0; c1 = n1; c2 = n2; c3 = n3;
    }

    // ---- output phases; expected output = Re(M), row-major, guarded.
    // Rows 2t (T) and 2t+1 (B), cols cA,cB -> contiguous float2 stores.
    float s0, cc0, s1, cc1;
    __sincosf(clamp02pi(pout[2 * t]),     &s0, &cc0);
    __sincosf(clamp02pi(pout[2 * t + 1]), &s1, &cc1);
    const int i0 = (2 * t) * 512 + cA;
    const int i1 = i0 + 512;
    if (i0 + 1 < out_size)
        *(float2*)(out + i0) = make_float2(cc0 * T0.x - s0 * T0.y,
                                           cc0 * T1.x - s0 * T1.y);
    if (i1 + 1 < out_size)
        *(float2*)(out + i1) = make_float2(cc1 * B0.x - s1 * B0.y,
                                           cc1 * B1.x - s1 * B1.y);
}

// ---------------------------------------------------------------------------
// Fallback (verbatim R5 kernel, known-passing) — used only if ws too small.
// ---------------------------------------------------------------------------
__global__ __launch_bounds__(256) void mesh_kernel(
    const float* __restrict__ pe, const float* __restrict__ po,
    const float* __restrict__ pout,
    const float* __restrict__ le, const float* __restrict__ ie,
    const float* __restrict__ lo, const float* __restrict__ io,
    float* __restrict__ out, const int out_size)
{
    const int p = threadIdx.x;
    const int b = blockIdx.x;

    __shared__ float4 P[2][256];

    P[0][p] = (p == b) ? make_float4(1.0f, 0.0f, 0.0f, 0.0f)
                       : make_float4(0.0f, 0.0f, 0.0f, 0.0f);
    P[1][p] = (p == b) ? make_float4(0.0f, 0.0f, 1.0f, 0.0f)
                       : make_float4(0.0f, 0.0f, 0.0f, 0.0f);

#pragma unroll 1
    for (int i = 0; i < 256; ++i) {
        const int e0 = (2 * i) * 256 + p, e1 = e0 + 256;
        const float pe0 = pe[e0], le0 = le[e0], ie0 = ie[e0];
        const float pe1 = pe[e1], le1 = le[e1], ie1 = ie[e1];
        float po0 = 0.0f, lo0 = 0.0f, io0 = 0.0f;
        float po1 = 0.0f, lo1 = 0.0f, io1 = 0.0f;
        if (p < 255) {
            const int o0 = (2 * i) * 255 + p, o1 = o0 + 255;
            po0 = po[o0]; lo0 = lo[o0]; io0 = io[o0];
            po1 = po[o1]; lo1 = lo[o1]; io1 = io[o1];
        }

        float4 v0 = P[0][p];
        float4 v1 = P[1][p];
#pragma unroll
        for (int j = 0; j < 2; ++j) {
            float s, c;
            __sincosf(clamp02pi(j ? pe1 : pe0), &s, &c);
            const float a  = sqrtf(1.0f - (j ? le1 : le0));
            const float tt = a * sqrtf(0.5f + (j ? ie1 : ie0));
            const float rr = a * sqrtf(0.5f - (j ? ie1 : ie0));
            {
                const float ptr_ = c * v0.x - s * v0.y;
                const float pti_ = c * v0.y + s * v0.x;
                v0 = make_float4(tt * ptr_ - rr * v0.w, tt * pti_ + rr * v0.z,
                                 tt * v0.z - rr * pti_, tt * v0.w + rr * ptr_);
            }
            {
                const float ptr_ = c * v1.x - s * v1.y;
                const float pti_ = c * v1.y + s * v1.x;
                v1 = make_float4(tt * ptr_ - rr * v1.w, tt * pti_ + rr * v1.z,
                                 tt * v1.z - rr * pti_, tt * v1.w + rr * ptr_);
            }
        }
        P[0][p] = v0;
        P[1][p] = v1;
        __syncthreads();

        if (p < 255) {
            float2 top0 = make_float2(P[0][p].z, P[0][p].w);
            float2 bot0 = make_float2(P[0][p + 1].x, P[0][p + 1].y);
            float2 top1 = make_float2(P[1][p].z, P[1][p].w);
            float2 bot1 = make_float2(P[1][p + 1].x, P[1][p + 1].y);
#pragma unroll
            for (int j = 0; j < 2; ++j) {
                float s, c;
                __sincosf(clamp02pi(j ? po1 : po0), &s, &c);
                const float a  = sqrtf(1.0f - (j ? lo1 : lo0));
                const float tt = a * sqrtf(0.5f + (j ? io1 : io0));
                const float rr = a * sqrtf(0.5f - (j ? io1 : io0));
                {
                    const float ptr_ = c * top0.x - s * top0.y;
                    const float pti_ = c * top0.y + s * top0.x;
                    const float nbx = tt * bot0.x - rr * pti_;
                    const float nby = tt * bot0.y + rr * ptr_;
                    top0 = make_float2(tt * ptr_ - rr * bot0.y, tt * pti_ + rr * bot0.x);
                    bot0 = make_float2(nbx, nby);
                }
                {
                    const float ptr_ = c * top1.x - s * top1.y;
                    const float pti_ = c * top1.y + s * top1.x;
                    const float nbx = tt * bot1.x - rr * pti_;
                    const float nby = tt * bot1.y + rr * ptr_;
                    top1 = make_float2(tt * ptr_ - rr * bot1.y, tt * pti_ + rr * bot1.x);
                    bot1 = make_float2(nbx, nby);
                }
            }
            P[0][p].z = top0.x; P[0][p].w = top0.y;
            P[0][p + 1].x = bot0.x; P[0][p + 1].y = bot0.y;
            P[1][p].z = top1.x; P[1][p].w = top1.y;
            P[1][p + 1].x = bot1.x; P[1][p + 1].y = bot1.y;
        }
        __syncthreads();
    }

    const float4 v0 = P[0][p];
    const float4 v1 = P[1][p];
    float s0, c0, s1, c1;
    __sincosf(clamp02pi(pout[2 * p]),     &s0, &c0);
    __sincosf(clamp02pi(pout[2 * p + 1]), &s1, &c1);

    float4 w0, w1;
    w0.x = c0 * v0.x - s0 * v0.y;  w0.y = c0 * v0.y + s0 * v0.x;
    w0.z = c0 * v1.x - s0 * v1.y;  w0.w = c0 * v1.y + s0 * v1.x;
    w1.x = c1 * v0.z - s1 * v0.w;  w1.y = c1 * v0.w + s1 * v0.z;
    w1.z = c1 * v1.z - s1 * v1.w;  w1.w = c1 * v1.w + s1 * v1.z;

    const int i0 = (2 * p) * 512 + 2 * b;
    const int i1 = (2 * p + 1) * 512 + 2 * b;
    if (i0 + 1 < out_size) *(float2*)(out + i0) = make_float2(w0.x, w0.z);
    if (i1 + 1 < out_size) *(float2*)(out + i1) = make_float2(w1.x, w1.z);
}

extern "C" void kernel_launch(void* const* d_in, const int* in_sizes, int n_in,
                              void* d_out, int out_size, void* d_ws, size_t ws_size,
                              hipStream_t stream)
{
    const float* pe   = (const float*)d_in[0];  // pc_even_phases  [512][256]
    const float* po   = (const float*)d_in[1];  // pc_odd_phases   [512][255]
    const float* pout = (const float*)d_in[2];  // pc_out_phases   [512]
    const float* le   = (const float*)d_in[3];  // mmi_loss_even   [512][256]
    const float* ie   = (const float*)d_in[4];  // mmi_imb_even    [512][256]
    const float* lo   = (const float*)d_in[5];  // mmi_loss_odd    [512][255]
    const float* io   = (const float*)d_in[6];  // mmi_imb_odd     [512][255]

    const size_t need = (size_t)256 * 1024 * sizeof(float4);  // 4 MB
    if (ws_size >= need) {
        float4* Mc = (float4*)d_ws;
        compose_kernel<<<256, 512, 0, stream>>>(pe, po, le, ie, lo, io, Mc);
        mesh_pair2_kernel<<<256, 256, 0, stream>>>(Mc, pout, (float*)d_out, out_size);
    } else {
        mesh_kernel<<<256, 256, 0, stream>>>(pe, po, pout, le, ie, lo, io,
                                             (float*)d_out, out_size);
    }
}